// Round 6
// baseline (679.457 us; speedup 1.0000x reference)
//
#include <hip/hip_runtime.h>
#include <hip/hip_bf16.h>

typedef __attribute__((ext_vector_type(8))) short short8;
typedef __attribute__((ext_vector_type(4))) float floatx4;
typedef __attribute__((ext_vector_type(4))) int int4v;
typedef __attribute__((ext_vector_type(4))) unsigned int uint4v;

#define MTBL 524288
#define HSTRIDE 72   // bf16 elems per h-row in LDS scratch (64+8 pad, 144 B = 16B-aligned)

union U4S8 { uint4v u; short8 s; };

// fp32 pair -> packed bf16 (round-to-nearest) via v_perm_b32: 3 VALU vs 5
static __device__ __forceinline__ unsigned int pack2bf(float a, float b) {
    unsigned int ua = __float_as_uint(a) + 0x8000u;
    unsigned int ub = __float_as_uint(b) + 0x8000u;
    return __builtin_amdgcn_perm(ub, ua, 0x07060302u);  // {ub.hi16, ua.hi16}
}
static __device__ __forceinline__ short bf1(float a) {
    return (short)((__float_as_uint(a) + 0x8000u) >> 16);
}

// relu + pack one 16-row C/D tile set into an h-row
static __device__ __forceinline__ void store_h(__hip_bfloat16* hrow,
                                               const floatx4* acc, int q) {
#pragma unroll
    for (int t = 0; t < 4; ++t) {
        uint2 pk;
        pk.x = pack2bf(fmaxf(acc[t][0], 0.f), fmaxf(acc[t][1], 0.f));
        pk.y = pack2bf(fmaxf(acc[t][2], 0.f), fmaxf(acc[t][3], 0.f));
        *(uint2*)(hrow + t * 16 + q * 4) = pk;
    }
}

// ---------------- Kernel P: fused prep (transpose idx + compress tables) ----------
// blocks [0, N/1024)          : transpose idx [N][16] -> idxT [16][N]
// blocks [N/1024, +16M/1024)  : compress tables fp32 -> packed-bf16 uint
__global__ __launch_bounds__(256) void ngp_prep(
    const int* __restrict__ idx, int* __restrict__ idxT,
    const floatx4* __restrict__ tab4, unsigned int* __restrict__ tblC, int N)
{
    const int TB = N >> 10;
    if ((int)blockIdx.x < TB) {
        const int t  = blockIdx.x * 256 + threadIdx.x;
        const int p0 = t * 4;
        const int4v* rows = (const int4v*)idx;
        int4v r[4][4];
#pragma unroll
        for (int p = 0; p < 4; ++p)
#pragma unroll
            for (int c = 0; c < 4; ++c)
                r[p][c] = __builtin_nontemporal_load(rows + (size_t)(p0 + p) * 4 + c);
#pragma unroll
        for (int c = 0; c < 4; ++c)
#pragma unroll
            for (int k = 0; k < 4; ++k) {
                const int h = c * 4 + k;
                int4v w;
                w[0] = r[0][c][k]; w[1] = r[1][c][k]; w[2] = r[2][c][k]; w[3] = r[3][c][k];
                *(int4v*)(idxT + (size_t)h * N + p0) = w;
            }
    } else {
        const int t = (blockIdx.x - TB) * 256 + threadIdx.x;   // entries 4t..4t+3
        floatx4 a = __builtin_nontemporal_load(tab4 + (size_t)2 * t);
        floatx4 b = __builtin_nontemporal_load(tab4 + (size_t)2 * t + 1);
        uint4v w;
        w[0] = pack2bf(a[0], a[1]);
        w[1] = pack2bf(a[2], a[3]);
        w[2] = pack2bf(b[0], b[1]);
        w[3] = pack2bf(b[2], b[3]);
        *(uint4v*)(tblC + (size_t)4 * t) = w;
    }
}

// ---------------- Kernel B: one-head-per-XCD gather phase ----------------
// head = (blk&7)*2 + phase; live table slice = 2 MiB packed < 4 MiB L2.
// NT loads/stores so streams don't evict the table slice.
__global__ __launch_bounds__(256) void ngp_gather_ph(
    const int* __restrict__ idxT, const unsigned int* __restrict__ tblC,
    unsigned int* __restrict__ xU, int N, int phase, int iters)
{
    const int h    = ((blockIdx.x & 7) << 1) | phase;
    const int slot = blockIdx.x >> 3;                 // 0..255
    const int* __restrict__ ih = idxT + (size_t)h * N;
    const unsigned int* __restrict__ th = tblC + (size_t)h * MTBL;
    unsigned int* __restrict__ xh = xU + (size_t)h * N;

    int p = slot * (N >> 8) + (threadIdx.x << 4);     // 16 points/thread/iter
    int4v iv[4];
#pragma unroll
    for (int j = 0; j < 4; ++j)
        iv[j] = __builtin_nontemporal_load((const int4v*)(ih + p + 4 * j));
    for (int it = 0; it < iters; ++it) {
        int4v nv[4];
        if (it + 1 < iters) {
#pragma unroll
            for (int j = 0; j < 4; ++j)
                nv[j] = __builtin_nontemporal_load((const int4v*)(ih + p + 4096 + 4 * j));
        }
#pragma unroll
        for (int j = 0; j < 4; ++j) {
            uint4v w;
            w[0] = th[iv[j][0]]; w[1] = th[iv[j][1]];
            w[2] = th[iv[j][2]]; w[3] = th[iv[j][3]];
            __builtin_nontemporal_store(w, (uint4v*)(xh + p + 4 * j));
        }
#pragma unroll
        for (int j = 0; j < 4; ++j) iv[j] = nv[j];
        p += 4096;
    }
}

// ---------------- Kernel C: MFMA MLP, 2 tiles (32 points) per wave-iteration ----
// (256,2): compiler free to ~256 VGPR -> no spill (R4 lesson: (256,4) forced
// VGPR=64 and spilled weight fragments, 970 MB of scratch traffic).
// LDS: single 24 KB buffer, weights during prologue then h-scratch (aliased).
__global__ __launch_bounds__(256, 2) void ngp_mlp(
    const unsigned int* __restrict__ xU,
    const float* __restrict__ W1, const float* __restrict__ b1,
    const float* __restrict__ W2, const float* __restrict__ b2,
    const float* __restrict__ W3, const float* __restrict__ b3,
    const float* __restrict__ W4, const float* __restrict__ b4,
    float* __restrict__ out, int N, int tiles_per_wave)
{
    __shared__ __align__(16) float sW[6144];          // 24 KB, weights -> h-scratch

    const int tid  = threadIdx.x;
    const int wave = tid >> 6;
    const int lane = tid & 63;
    const int q = lane >> 4;
    const int m = lane & 15;

    short8 A1[4], A2[4][2], A3[4][2], A4[2];
    floatx4 C1[4], C2[4], C3[4], C4;

    // ---- stage A: W1 (2048) + W2 (4096) ----
    for (int i = tid; i < 2048; i += 256) sW[i] = W1[i];
    for (int i = tid; i < 4096; i += 256) sW[2048 + i] = W2[i];
    __syncthreads();
#pragma unroll
    for (int t = 0; t < 4; ++t) {
        short8 a;
#pragma unroll
        for (int j = 0; j < 8; ++j)
            a[j] = bf1(sW[(q * 8 + j) * 64 + t * 16 + m]);
        A1[t] = a;
    }
#pragma unroll
    for (int t = 0; t < 4; ++t)
#pragma unroll
        for (int c = 0; c < 2; ++c) {
            short8 a;
#pragma unroll
            for (int j = 0; j < 8; ++j)
                a[j] = bf1(sW[2048 + (c * 32 + q * 8 + j) * 64 + t * 16 + m]);
            A2[t][c] = a;
        }
    __syncthreads();

    // ---- stage B: W3 (4096) + W4 (192) + biases (195) ----
    for (int i = tid; i < 4096; i += 256) sW[i] = W3[i];
    if (tid < 192) sW[4096 + tid] = W4[tid];
    if (tid < 64)       sW[4288 + tid] = b1[tid];
    else if (tid < 128) sW[4288 + tid] = b2[tid - 64];
    else if (tid < 192) sW[4288 + tid] = b3[tid - 128];
    else if (tid < 195) sW[4288 + tid] = b4[tid - 192];
    __syncthreads();
#pragma unroll
    for (int t = 0; t < 4; ++t)
#pragma unroll
        for (int c = 0; c < 2; ++c) {
            short8 a;
#pragma unroll
            for (int j = 0; j < 8; ++j)
                a[j] = bf1(sW[(c * 32 + q * 8 + j) * 64 + t * 16 + m]);
            A3[t][c] = a;
        }
#pragma unroll
    for (int c = 0; c < 2; ++c) {
        short8 a;
#pragma unroll
        for (int j = 0; j < 8; ++j)
            a[j] = (m < 3) ? bf1(sW[4096 + (c * 32 + q * 8 + j) * 3 + m]) : (short)0;
        A4[c] = a;
    }
#pragma unroll
    for (int t = 0; t < 4; ++t)
#pragma unroll
        for (int r = 0; r < 4; ++r) {
            C1[t][r] = sW[4288 + t * 16 + q * 4 + r];
            C2[t][r] = sW[4288 + 64 + t * 16 + q * 4 + r];
            C3[t][r] = sW[4288 + 128 + t * 16 + q * 4 + r];
        }
#pragma unroll
    for (int r = 0; r < 4; ++r)
        C4[r] = (q == 0 && r < 3) ? sW[4288 + 192 + r] : 0.0f;
    __syncthreads();   // weights fully extracted; sW now re-used as h-scratch

    // per-wave scratch: 32 rows (2 tiles) x HSTRIDE bf16 = 4608 B/wave, 18.4 KB total
    __hip_bfloat16* hA = (__hip_bfloat16*)sW + wave * (32 * HSTRIDE) + m * HSTRIDE;
    __hip_bfloat16* hB = hA + 16 * HSTRIDE;

    const int gw = blockIdx.x * 4 + wave;
    const int tile0 = gw * tiles_per_wave;
    const unsigned int* xr = xU + (size_t)(q * 4) * N + m;

    uint4v curA, curB;
    {
        const int cA = tile0 * 16, cB = cA + 16;
        curA[0] = xr[cA]; curA[1] = xr[(size_t)N + cA];
        curA[2] = xr[(size_t)2 * N + cA]; curA[3] = xr[(size_t)3 * N + cA];
        curB[0] = xr[cB]; curB[1] = xr[(size_t)N + cB];
        curB[2] = xr[(size_t)2 * N + cB]; curB[3] = xr[(size_t)3 * N + cB];
    }

    for (int it = 0; it < tiles_per_wave; it += 2) {
        const int pA = (tile0 + it) * 16;
        const bool more = (it + 2) < tiles_per_wave;

        U4S8 ba; ba.u = curA; const short8 BxA = ba.s;
        U4S8 bb; bb.u = curB; const short8 BxB = bb.s;

        uint4v nA, nB;
        if (more) {
            const int cA = pA + 32, cB = pA + 48;
            nA[0] = xr[cA]; nA[1] = xr[(size_t)N + cA];
            nA[2] = xr[(size_t)2 * N + cA]; nA[3] = xr[(size_t)3 * N + cA];
            nB[0] = xr[cB]; nB[1] = xr[(size_t)N + cB];
            nB[2] = xr[(size_t)2 * N + cB]; nB[3] = xr[(size_t)3 * N + cB];
        }

        // ---- layer 1 (two independent tiles) ----
        floatx4 aA[4], aB[4];
#pragma unroll
        for (int t = 0; t < 4; ++t) {
            aA[t] = __builtin_amdgcn_mfma_f32_16x16x32_bf16(A1[t], BxA, C1[t], 0, 0, 0);
            aB[t] = __builtin_amdgcn_mfma_f32_16x16x32_bf16(A1[t], BxB, C1[t], 0, 0, 0);
        }
        store_h(hA, aA, q); store_h(hB, aB, q);
        short8 fA0 = *(const short8*)(hA + q * 8);
        short8 fA1 = *(const short8*)(hA + 32 + q * 8);
        short8 fB0 = *(const short8*)(hB + q * 8);
        short8 fB1 = *(const short8*)(hB + 32 + q * 8);

        // ---- layer 2 ----
#pragma unroll
        for (int t = 0; t < 4; ++t) {
            aA[t] = __builtin_amdgcn_mfma_f32_16x16x32_bf16(A2[t][0], fA0, C2[t], 0, 0, 0);
            aA[t] = __builtin_amdgcn_mfma_f32_16x16x32_bf16(A2[t][1], fA1, aA[t], 0, 0, 0);
            aB[t] = __builtin_amdgcn_mfma_f32_16x16x32_bf16(A2[t][0], fB0, C2[t], 0, 0, 0);
            aB[t] = __builtin_amdgcn_mfma_f32_16x16x32_bf16(A2[t][1], fB1, aB[t], 0, 0, 0);
        }
        store_h(hA, aA, q); store_h(hB, aB, q);
        fA0 = *(const short8*)(hA + q * 8);
        fA1 = *(const short8*)(hA + 32 + q * 8);
        fB0 = *(const short8*)(hB + q * 8);
        fB1 = *(const short8*)(hB + 32 + q * 8);

        // ---- layer 3 ----
#pragma unroll
        for (int t = 0; t < 4; ++t) {
            aA[t] = __builtin_amdgcn_mfma_f32_16x16x32_bf16(A3[t][0], fA0, C3[t], 0, 0, 0);
            aA[t] = __builtin_amdgcn_mfma_f32_16x16x32_bf16(A3[t][1], fA1, aA[t], 0, 0, 0);
            aB[t] = __builtin_amdgcn_mfma_f32_16x16x32_bf16(A3[t][0], fB0, C3[t], 0, 0, 0);
            aB[t] = __builtin_amdgcn_mfma_f32_16x16x32_bf16(A3[t][1], fB1, aB[t], 0, 0, 0);
        }
        store_h(hA, aA, q); store_h(hB, aB, q);
        fA0 = *(const short8*)(hA + q * 8);
        fA1 = *(const short8*)(hA + 32 + q * 8);
        fB0 = *(const short8*)(hB + q * 8);
        fB1 = *(const short8*)(hB + 32 + q * 8);

        // ---- layer 4 ----
        floatx4 oA, oB;
        oA = __builtin_amdgcn_mfma_f32_16x16x32_bf16(A4[0], fA0, C4, 0, 0, 0);
        oA = __builtin_amdgcn_mfma_f32_16x16x32_bf16(A4[1], fA1, oA, 0, 0, 0);
        oB = __builtin_amdgcn_mfma_f32_16x16x32_bf16(A4[0], fB0, C4, 0, 0, 0);
        oB = __builtin_amdgcn_mfma_f32_16x16x32_bf16(A4[1], fB1, oB, 0, 0, 0);

        if (q == 0) {
            const int pnA = pA + m, pnB = pA + 16 + m;
            out[pnA * 3 + 0] = oA[0];
            out[pnA * 3 + 1] = oA[1];
            out[pnA * 3 + 2] = oA[2];
            out[pnB * 3 + 0] = oB[0];
            out[pnB * 3 + 1] = oB[1];
            out[pnB * 3 + 2] = oB[2];
        }

        curA = nA; curB = nB;
    }
}

// ---------------- Fallback: R1 fused kernel (ws too small; not expected) ---------
__global__ __launch_bounds__(256, 2) void ngp_fused(
    const int* __restrict__ idx,
    const float* __restrict__ tables,
    const float* __restrict__ W1, const float* __restrict__ b1,
    const float* __restrict__ W2, const float* __restrict__ b2,
    const float* __restrict__ W3, const float* __restrict__ b3,
    const float* __restrict__ W4, const float* __restrict__ b4,
    float* __restrict__ out, int tiles_per_wave)
{
    __shared__ float sW1[2048];
    __shared__ float sW2[4096];
    __shared__ float sW3[4096];
    __shared__ float sW4[192];
    __shared__ float sB[200];
    __shared__ __hip_bfloat16 sH[4][16 * HSTRIDE];

    const int tid = threadIdx.x;
    for (int i = tid; i < 2048; i += 256) sW1[i] = W1[i];
    for (int i = tid; i < 4096; i += 256) sW2[i] = W2[i];
    for (int i = tid; i < 4096; i += 256) sW3[i] = W3[i];
    if (tid < 192) sW4[tid] = W4[tid];
    if (tid < 64)       sB[tid] = b1[tid];
    else if (tid < 128) sB[tid] = b2[tid - 64];
    else if (tid < 192) sB[tid] = b3[tid - 128];
    else if (tid < 195) sB[tid] = b4[tid - 192];
    __syncthreads();

    const int wave = tid >> 6;
    const int lane = tid & 63;
    const int q = lane >> 4;
    const int m = lane & 15;

    short8 A1[4], A2[4][2], A3[4][2], A4[2];
#pragma unroll
    for (int t = 0; t < 4; ++t) {
        short8 a;
#pragma unroll
        for (int j = 0; j < 8; ++j)
            a[j] = bf1(sW1[(q * 8 + j) * 64 + t * 16 + m]);
        A1[t] = a;
    }
#pragma unroll
    for (int t = 0; t < 4; ++t)
#pragma unroll
        for (int c = 0; c < 2; ++c) {
            short8 a, a3;
#pragma unroll
            for (int j = 0; j < 8; ++j) {
                a[j]  = bf1(sW2[(c * 32 + q * 8 + j) * 64 + t * 16 + m]);
                a3[j] = bf1(sW3[(c * 32 + q * 8 + j) * 64 + t * 16 + m]);
            }
            A2[t][c] = a;
            A3[t][c] = a3;
        }
#pragma unroll
    for (int c = 0; c < 2; ++c) {
        short8 a;
#pragma unroll
        for (int j = 0; j < 8; ++j)
            a[j] = (m < 3) ? bf1(sW4[(c * 32 + q * 8 + j) * 3 + m]) : (short)0;
        A4[c] = a;
    }

    floatx4 C1[4], C2[4], C3[4], C4;
#pragma unroll
    for (int t = 0; t < 4; ++t)
#pragma unroll
        for (int r = 0; r < 4; ++r) {
            C1[t][r] = sB[t * 16 + q * 4 + r];
            C2[t][r] = sB[64 + t * 16 + q * 4 + r];
            C3[t][r] = sB[128 + t * 16 + q * 4 + r];
        }
#pragma unroll
    for (int r = 0; r < 4; ++r)
        C4[r] = (q == 0 && r < 3) ? sB[192 + r] : 0.0f;

    __hip_bfloat16* hrow = &sH[wave][m * HSTRIDE];
    const int4*   idx4 = (const int4*)idx;
    const float2* tbl  = (const float2*)tables;

    const int gw = blockIdx.x * 4 + wave;
    const int tile0 = gw * tiles_per_wave;

    int4 iv = idx4[(tile0 * 16 + m) * 4 + q];
    float2 g0 = tbl[(q * 4 + 0) * MTBL + iv.x];
    float2 g1 = tbl[(q * 4 + 1) * MTBL + iv.y];
    float2 g2 = tbl[(q * 4 + 2) * MTBL + iv.z];
    float2 g3 = tbl[(q * 4 + 3) * MTBL + iv.w];

    for (int it = 0; it < tiles_per_wave; ++it) {
        const int pbase = (tile0 + it) * 16;
        const bool more = (it + 1) < tiles_per_wave;

        short8 Bx;
        {
            unsigned int p0 = pack2bf(g0.x, g0.y);
            unsigned int p1 = pack2bf(g1.x, g1.y);
            unsigned int p2 = pack2bf(g2.x, g2.y);
            unsigned int p3 = pack2bf(g3.x, g3.y);
            Bx[0] = (short)(p0 & 0xFFFF); Bx[1] = (short)(p0 >> 16);
            Bx[2] = (short)(p1 & 0xFFFF); Bx[3] = (short)(p1 >> 16);
            Bx[4] = (short)(p2 & 0xFFFF); Bx[5] = (short)(p2 >> 16);
            Bx[6] = (short)(p3 & 0xFFFF); Bx[7] = (short)(p3 >> 16);
        }

        int4 ivn;
        if (more) ivn = idx4[((pbase + 16) + m) * 4 + q];

        floatx4 acc[4];
#pragma unroll
        for (int t = 0; t < 4; ++t)
            acc[t] = __builtin_amdgcn_mfma_f32_16x16x32_bf16(A1[t], Bx, C1[t], 0, 0, 0);

        store_h(hrow, acc, q);
        short8 Bh0 = *(const short8*)(hrow + q * 8);
        short8 Bh1 = *(const short8*)(hrow + 32 + q * 8);

#pragma unroll
        for (int t = 0; t < 4; ++t) {
            acc[t] = __builtin_amdgcn_mfma_f32_16x16x32_bf16(A2[t][0], Bh0, C2[t], 0, 0, 0);
            acc[t] = __builtin_amdgcn_mfma_f32_16x16x32_bf16(A2[t][1], Bh1, acc[t], 0, 0, 0);
        }

        if (more) {
            g0 = tbl[(q * 4 + 0) * MTBL + ivn.x];
            g1 = tbl[(q * 4 + 1) * MTBL + ivn.y];
            g2 = tbl[(q * 4 + 2) * MTBL + ivn.z];
            g3 = tbl[(q * 4 + 3) * MTBL + ivn.w];
        }

        store_h(hrow, acc, q);
        Bh0 = *(const short8*)(hrow + q * 8);
        Bh1 = *(const short8*)(hrow + 32 + q * 8);

#pragma unroll
        for (int t = 0; t < 4; ++t) {
            acc[t] = __builtin_amdgcn_mfma_f32_16x16x32_bf16(A3[t][0], Bh0, C3[t], 0, 0, 0);
            acc[t] = __builtin_amdgcn_mfma_f32_16x16x32_bf16(A3[t][1], Bh1, acc[t], 0, 0, 0);
        }

        store_h(hrow, acc, q);
        Bh0 = *(const short8*)(hrow + q * 8);
        Bh1 = *(const short8*)(hrow + 32 + q * 8);

        floatx4 o;
        o = __builtin_amdgcn_mfma_f32_16x16x32_bf16(A4[0], Bh0, C4, 0, 0, 0);
        o = __builtin_amdgcn_mfma_f32_16x16x32_bf16(A4[1], Bh1, o, 0, 0, 0);

        if (q == 0) {
            const int pn = pbase + m;
            out[pn * 3 + 0] = o[0];
            out[pn * 3 + 1] = o[1];
            out[pn * 3 + 2] = o[2];
        }
    }
}

extern "C" void kernel_launch(void* const* d_in, const int* in_sizes, int n_in,
                              void* d_out, int out_size, void* d_ws, size_t ws_size,
                              hipStream_t stream) {
    const int*   idx    = (const int*)d_in[0];
    const float* tables = (const float*)d_in[1];
    const float* W1 = (const float*)d_in[2];
    const float* b1 = (const float*)d_in[3];
    const float* W2 = (const float*)d_in[4];
    const float* b2 = (const float*)d_in[5];
    const float* W3 = (const float*)d_in[6];
    const float* b3 = (const float*)d_in[7];
    const float* W4 = (const float*)d_in[8];
    const float* b4 = (const float*)d_in[9];
    float* out = (float*)d_out;

    const int N = in_sizes[0] / 16;            // points (2,097,152)
    const int total_tiles = N / 16;

    const size_t idxT_bytes = (size_t)16 * N * 4;           // 128 MiB
    const size_t xU_bytes   = (size_t)16 * N * 4;           // 128 MiB
    const size_t tblC_bytes = (size_t)16 * MTBL * 4;        // 32 MiB
    const size_t need = idxT_bytes + xU_bytes + tblC_bytes;

    if (ws_size >= need) {
        int*          idxT = (int*)d_ws;
        unsigned int* xU   = (unsigned int*)((char*)d_ws + idxT_bytes);
        unsigned int* tblC = (unsigned int*)((char*)d_ws + idxT_bytes + xU_bytes);

        // P: fused transpose + compress
        const int TB = N >> 10;                  // 2048 transpose blocks
        const int CB = (16 * MTBL) >> 10;        // 8192 compress blocks
        ngp_prep<<<TB + CB, 256, 0, stream>>>(idx, idxT, (const floatx4*)tables,
                                              tblC, N);
        // B: two gather phases, one head per XCD each
        const int iters = (N >> 8) >> 12;        // 16 pts/thread/iter -> 2
        ngp_gather_ph<<<2048, 256, 0, stream>>>(idxT, tblC, xU, N, 0, iters);
        ngp_gather_ph<<<2048, 256, 0, stream>>>(idxT, tblC, xU, N, 1, iters);
        // C: MFMA MLP (2 tiles per wave-iteration)
        const int blocks = 2048;
        const int tiles_per_wave = total_tiles / (blocks * 4);
        ngp_mlp<<<blocks, 256, 0, stream>>>(xU, W1, b1, W2, b2, W3, b3, W4, b4,
                                            out, N, tiles_per_wave);
    } else {
        const int blocks = 2048;
        const int tiles_per_wave = total_tiles / (blocks * 4);
        ngp_fused<<<blocks, 256, 0, stream>>>(idx, tables, W1, b1, W2, b2, W3, b3,
                                              W4, b4, out, tiles_per_wave);
    }
}